// Round 16
// baseline (86.623 us; speedup 1.0000x reference)
//
#include <hip/hip_runtime.h>

#define NSEQ 2048
#define NB 2
#define NH 8
#define HD 64
#define DMODEL 1024
#define DINNER 512   // NH*HD

// partial slot for k-split tiles: O[64][64] f32 + m[64] + l[64]
#define SLOT_F 4224

typedef __attribute__((ext_vector_type(8))) short bf16x8;
typedef __attribute__((ext_vector_type(4))) float f32x4;

__device__ __forceinline__ ushort f2bf(float f) {
  uint u = __float_as_uint(f);
  uint r = (u + 0x7fffu + ((u >> 16) & 1u)) >> 16;
  return (ushort)r;
}

// async global->LDS, 16B per lane; LDS dest is wave-uniform base (+lane*16 by HW)
__device__ __forceinline__ void gld16(const ushort* g, ushort* l) {
  __builtin_amdgcn_global_load_lds(
      (const __attribute__((address_space(1))) uint*)g,
      (__attribute__((address_space(3))) uint*)l, 16, 0, 0);
}

// ---------------- prep: x-cast + both weight transposes, ONE launch --------
// id < 512:        xsw tile (mt=id>>4 of 32, kt=id&15 of 16): 128 rows x 64 k
// 512 <= id < 672: WT1sw tile (nt64=(id-512)>>4 of 10, kt=(id-512)&15 of 16)
// 672 <= id < 800: WoTsw tile (nt64=(id-672)>>3 of 16, kt=(id-672)&7 of 8)
// All tile images are the exact swizzled LDS layout: row*64 + ((chunk^(row&7))*8)
__global__ __launch_bounds__(256) void prep_kernel(
    const float* __restrict__ x, const float* __restrict__ Wq,
    const float* __restrict__ Wkv, const float* __restrict__ Wo,
    ushort* __restrict__ xsw, ushort* __restrict__ WT1sw,
    ushort* __restrict__ WoTsw) {
  __shared__ float t[64][65];
  const int id = blockIdx.x;
  const int tid = threadIdx.x;
  if (id < 512) {
    const int mt = id >> 4, kt = id & 15;
    ushort* tile = xsw + (size_t)(mt * 16 + kt) * 8192;
#pragma unroll
    for (int i = 0; i < 4; ++i) {
      const int cix = i * 256 + tid;
      const int row = cix >> 3, j = cix & 7;
      const float* p = x + (size_t)(mt * 128 + row) * DMODEL + kt * 64 + j * 8;
      float4 a = *(const float4*)p;
      float4 b = *(const float4*)(p + 4);
      uint u0, u1, u2, u3;
      asm("v_cvt_pk_bf16_f32 %0, %1, %2" : "=v"(u0) : "v"(a.x), "v"(a.y));
      asm("v_cvt_pk_bf16_f32 %0, %1, %2" : "=v"(u1) : "v"(a.z), "v"(a.w));
      asm("v_cvt_pk_bf16_f32 %0, %1, %2" : "=v"(u2) : "v"(b.x), "v"(b.y));
      asm("v_cvt_pk_bf16_f32 %0, %1, %2" : "=v"(u3) : "v"(b.z), "v"(b.w));
      uint4 v; v.x = u0; v.y = u1; v.z = u2; v.w = u3;
      *(uint4*)(tile + (size_t)row * 64 + ((j ^ (row & 7)) << 3)) = v;
    }
    return;
  }
  const float *srcA, *srcB;
  int ldA, ldB, nsplit, k0, n0;
  ushort* tile;
  if (id < 672) {
    const int u = id - 512;
    const int nt = u >> 4, kt = u & 15;
    k0 = kt * 64; n0 = nt * 64;
    srcA = Wq; srcB = Wkv; ldA = 512; ldB = 128; nsplit = 512;
    tile = WT1sw + (size_t)(nt * 16 + kt) * 4096;
  } else {
    const int u = id - 672;
    const int nt = u >> 3, kt = u & 7;
    k0 = kt * 64; n0 = nt * 64;
    srcA = Wo; srcB = Wo; ldA = 1024; ldB = 1024; nsplit = 1024;
    tile = WoTsw + (size_t)(nt * 8 + kt) * 4096;
  }
  const float* src; int ld, nb;
  if (n0 < nsplit) { src = srcA; ld = ldA; nb = n0; }
  else { src = srcB; ld = ldB; nb = n0 - nsplit; }
  const int r = tid >> 4;
  const int c = (tid & 15) * 4;
#pragma unroll
  for (int rr = r; rr < 64; rr += 16) {
    float4 v = *(const float4*)(src + (size_t)(k0 + rr) * ld + nb + c);
    t[rr][c + 0] = v.x; t[rr][c + 1] = v.y; t[rr][c + 2] = v.z; t[rr][c + 3] = v.w;
  }
  __syncthreads();
#pragma unroll
  for (int rr = r; rr < 64; rr += 16) {
    ushort4 o;
    o.x = f2bf(t[c + 0][rr]); o.y = f2bf(t[c + 1][rr]);
    o.z = f2bf(t[c + 2][rr]); o.w = f2bf(t[c + 3][rr]);
    *(ushort4*)(tile + (size_t)rr * 64 + (((c >> 3) ^ (rr & 7)) << 3) + (c & 7)) = o;
  }
}

// ---------------- Kernel: QKV GEMM, 128x128 gld16 dbuf pipeline -------------
// grid (32,5). A from xsw tiles; B (128 n-rows) from two WT1sw tiles.
__global__ __launch_bounds__(256) void qkv_mfma_kernel(
    const ushort* __restrict__ xsw, const ushort* __restrict__ WT1sw,
    ushort* __restrict__ qb, ushort* __restrict__ ksw, ushort* __restrict__ vsw) {
  __shared__ ushort As[2 * 128 * 64];
  __shared__ ushort Bs[2 * 128 * 64];
  const int tid = threadIdx.x;
  const int mt = blockIdx.x;    // m0 = mt*128
  const int nt = blockIdx.y;    // n0 = nt*128
  const int lane = tid & 63;
  const int w = tid >> 6;
  const int wr = w >> 1, wc = w & 1;
  const int lr = lane & 15, lg = lane >> 4;
  f32x4 acc[4][4];
#pragma unroll
  for (int a = 0; a < 4; ++a)
#pragma unroll
    for (int b = 0; b < 4; ++b) acc[a][b] = (f32x4){0.f, 0.f, 0.f, 0.f};

#define QISSUE(kt, buf)                                                       \
  {                                                                           \
    const ushort* _as =                                                       \
        xsw + (size_t)(mt * 16 + (kt)) * 8192 + w * 2048 + lane * 8;          \
    ushort* _ad = As + (buf) * 8192 + w * 2048;                               \
    gld16(_as, _ad);                                                          \
    gld16(_as + 512, _ad + 512);                                              \
    gld16(_as + 1024, _ad + 1024);                                            \
    gld16(_as + 1536, _ad + 1536);                                            \
    const ushort* _bs = WT1sw +                                               \
        (size_t)((nt * 2 + (w >> 1)) * 16 + (kt)) * 4096 + (w & 1) * 2048 +   \
        lane * 8;                                                             \
    ushort* _bd = Bs + (buf) * 8192 + w * 2048;                               \
    gld16(_bs, _bd);                                                          \
    gld16(_bs + 512, _bd + 512);                                              \
    gld16(_bs + 1024, _bd + 1024);                                            \
    gld16(_bs + 1536, _bd + 1536);                                            \
  }

  QISSUE(0, 0);
  QISSUE(1, 1);
  int cur = 0;
  for (int i = 0; i < 16; ++i) {
    if (i < 15) {
      asm volatile("s_waitcnt vmcnt(8)" ::: "memory");
    } else {
      asm volatile("s_waitcnt vmcnt(0)" ::: "memory");
    }
    __builtin_amdgcn_sched_barrier(0);
    __builtin_amdgcn_s_barrier();
    const char* Ac = (const char*)(As + cur * 8192);
    const char* Bc = (const char*)(Bs + cur * 8192);
    __builtin_amdgcn_s_setprio(1);
#pragma unroll
    for (int kk = 0; kk < 2; ++kk) {
      bf16x8 af[4], bfr[4];
#pragma unroll
      for (int mi = 0; mi < 4; ++mi) {
        const int r = wr * 64 + mi * 16 + lr;
        af[mi] = *(const bf16x8*)(Ac + r * 128 + (((kk * 4 + lg) ^ (r & 7)) << 4));
      }
#pragma unroll
      for (int ni = 0; ni < 4; ++ni) {
        const int r = wc * 64 + ni * 16 + lr;
        bfr[ni] = *(const bf16x8*)(Bc + r * 128 + (((kk * 4 + lg) ^ (r & 7)) << 4));
      }
#pragma unroll
      for (int mi = 0; mi < 4; ++mi)
#pragma unroll
        for (int ni = 0; ni < 4; ++ni)
          acc[mi][ni] = __builtin_amdgcn_mfma_f32_16x16x32_bf16(af[mi], bfr[ni],
                                                                acc[mi][ni], 0, 0, 0);
    }
    __builtin_amdgcn_s_setprio(0);
    __builtin_amdgcn_sched_barrier(0);
    __builtin_amdgcn_s_barrier();
    if (i + 2 < 16) QISSUE(i + 2, cur);
    cur ^= 1;
  }
#undef QISSUE
#pragma unroll
  for (int mi = 0; mi < 4; ++mi)
#pragma unroll
    for (int ni = 0; ni < 4; ++ni) {
      const int n = nt * 128 + wc * 64 + ni * 16 + lr;
#pragma unroll
      for (int r = 0; r < 4; ++r) {
        const int m = mt * 128 + wr * 64 + mi * 16 + lg * 4 + r;
        const int bb = m >> 11, key = m & (NSEQ - 1);
        const float v = acc[mi][ni][r];
        if (n < DINNER) {
          const int h = n >> 6, d = n & 63;
          qb[((size_t)((bb * NH + h) * NSEQ) + key) * HD + d] = f2bf(v * 0.125f);
        } else if (n < DINNER + HD) {
          const int d = n - DINNER;
          const int t = key >> 6, row = key & 63;
          ksw[(size_t)((bb * 32 + t) * 64 + row) * 64 +
              (((d >> 3) ^ (row & 7)) << 3) + (d & 7)] = f2bf(v);
        } else {
          const int d = n - DINNER - HD;
          const int pr = key >> 7, kk = key & 127;
          vsw[(size_t)((bb * 16 + pr) * 64 + d) * 128 +
              (((kk >> 3) ^ (d & 15)) << 3) + (kk & 7)] = f2bf(v);
        }
      }
    }
}

// ---------------- Kernel: out GEMM, 128x128 gld16 dbuf pipeline + bias -----
// grid (32,8). A from obsw tiles (mt, kt 0..7); B from two WoTsw tiles.
__global__ __launch_bounds__(256) void out_mfma_kernel(
    const ushort* __restrict__ obsw, const ushort* __restrict__ WoTsw,
    const float* __restrict__ bo, float* __restrict__ out) {
  __shared__ ushort As[2 * 128 * 64];
  __shared__ ushort Bs[2 * 128 * 64];
  const int tid = threadIdx.x;
  const int mt = blockIdx.x;   // m0 = mt*128
  const int nt = blockIdx.y;   // n0 = nt*128
  const int lane = tid & 63;
  const int w = tid >> 6;
  const int wr = w >> 1, wc = w & 1;
  const int lr = lane & 15, lg = lane >> 4;
  f32x4 acc[4][4];
#pragma unroll
  for (int a = 0; a < 4; ++a)
#pragma unroll
    for (int b = 0; b < 4; ++b) acc[a][b] = (f32x4){0.f, 0.f, 0.f, 0.f};

#define OISSUE(kt, buf)                                                       \
  {                                                                           \
    const ushort* _as =                                                       \
        obsw + (size_t)(mt * 8 + (kt)) * 8192 + w * 2048 + lane * 8;          \
    ushort* _ad = As + (buf) * 8192 + w * 2048;                               \
    gld16(_as, _ad);                                                          \
    gld16(_as + 512, _ad + 512);                                              \
    gld16(_as + 1024, _ad + 1024);                                            \
    gld16(_as + 1536, _ad + 1536);                                            \
    const ushort* _bs = WoTsw +                                               \
        (size_t)((nt * 2 + (w >> 1)) * 8 + (kt)) * 4096 + (w & 1) * 2048 +    \
        lane * 8;                                                             \
    ushort* _bd = Bs + (buf) * 8192 + w * 2048;                               \
    gld16(_bs, _bd);                                                          \
    gld16(_bs + 512, _bd + 512);                                              \
    gld16(_bs + 1024, _bd + 1024);                                            \
    gld16(_bs + 1536, _bd + 1536);                                            \
  }

  OISSUE(0, 0);
  OISSUE(1, 1);
  int cur = 0;
  for (int i = 0; i < 8; ++i) {
    if (i < 7) {
      asm volatile("s_waitcnt vmcnt(8)" ::: "memory");
    } else {
      asm volatile("s_waitcnt vmcnt(0)" ::: "memory");
    }
    __builtin_amdgcn_sched_barrier(0);
    __builtin_amdgcn_s_barrier();
    const char* Ac = (const char*)(As + cur * 8192);
    const char* Bc = (const char*)(Bs + cur * 8192);
    __builtin_amdgcn_s_setprio(1);
#pragma unroll
    for (int kk = 0; kk < 2; ++kk) {
      bf16x8 af[4], bfr[4];
#pragma unroll
      for (int mi = 0; mi < 4; ++mi) {
        const int r = wr * 64 + mi * 16 + lr;
        af[mi] = *(const bf16x8*)(Ac + r * 128 + (((kk * 4 + lg) ^ (r & 7)) << 4));
      }
#pragma unroll
      for (int ni = 0; ni < 4; ++ni) {
        const int r = wc * 64 + ni * 16 + lr;
        bfr[ni] = *(const bf16x8*)(Bc + r * 128 + (((kk * 4 + lg) ^ (r & 7)) << 4));
      }
#pragma unroll
      for (int mi = 0; mi < 4; ++mi)
#pragma unroll
        for (int ni = 0; ni < 4; ++ni)
          acc[mi][ni] = __builtin_amdgcn_mfma_f32_16x16x32_bf16(af[mi], bfr[ni],
                                                                acc[mi][ni], 0, 0, 0);
    }
    __builtin_amdgcn_s_setprio(0);
    __builtin_amdgcn_sched_barrier(0);
    __builtin_amdgcn_s_barrier();
    if (i + 2 < 8) OISSUE(i + 2, cur);
    cur ^= 1;
  }
#undef OISSUE
#pragma unroll
  for (int mi = 0; mi < 4; ++mi)
#pragma unroll
    for (int ni = 0; ni < 4; ++ni) {
      const int n = nt * 128 + wc * 64 + ni * 16 + lr;
      const float bias = bo[n];
#pragma unroll
      for (int r = 0; r < 4; ++r) {
        const int m = mt * 128 + wr * 64 + mi * 16 + lg * 4 + r;
        out[(size_t)m * DMODEL + n] = acc[mi][ni][r] + bias;
      }
    }
}

// ---------------- Kernel: causal flash attention (R8-best, unchanged) ------
__global__ __launch_bounds__(256) void attn_mfma_kernel(
    const ushort* __restrict__ qb, const ushort* __restrict__ ksw,
    const ushort* __restrict__ vsw, const float* __restrict__ rpb,
    ushort* __restrict__ obsw, float* __restrict__ scratch) {
  __shared__ ushort Ks[2 * 128 * 64];
  __shared__ ushort Vs[2 * 64 * 128];
  __shared__ ushort Ps[4 * 16 * 128];
  const int tid = threadIdx.x;
  const int lane = tid & 63;
  const int w = tid >> 6;
  const int id = blockIdx.x;
  const int bh = id & 15;
  int qt, ch, p0, p1, partial;
  if (id < 256) {
    qt = 16 + (id >> 4); ch = 0; p0 = 0; p1 = 8; partial = 1;
  } else if (id < 512) {
    qt = 31 - ((id - 256) >> 4); ch = 1; p0 = 8; p1 = (qt >> 1) + 1; partial = 1;
  } else {
    qt = 15 - ((id - 512) >> 4); ch = 0; p0 = 0; p1 = (qt >> 1) + 1; partial = 0;
  }
  const int bb = bh >> 3, h = bh & 7;
  const int q0 = qt * 64;
  const int lr = lane & 15;
  const int lg = lane >> 4;
  const int pdiag = qt >> 1;

  const ushort* kpair = ksw + (size_t)bb * 32 * 64 * 64;
  const ushort* vpair = vsw + (size_t)bb * 16 * 64 * 128;
  const ushort* ksrcw = kpair + w * 2048 + lane * 8;
  const ushort* vsrcw = vpair + w * 2048 + lane * 8;
  ushort* kdstw = Ks + w * 2048;
  ushort* vdstw = Vs + w * 2048;

#define ISSUE(pp, bsel)                                                     \
  {                                                                         \
    const ushort* _ks = ksrcw + (size_t)(pp) * 8192;                        \
    const ushort* _vs = vsrcw + (size_t)(pp) * 8192;                        \
    ushort* _kd = kdstw + (bsel) * 8192;                                    \
    ushort* _vd = vdstw + (bsel) * 8192;                                    \
    gld16(_ks + 0 * 512, _kd + 0 * 512);                                    \
    gld16(_ks + 1 * 512, _kd + 1 * 512);                                    \
    gld16(_ks + 2 * 512, _kd + 2 * 512);                                    \
    gld16(_ks + 3 * 512, _kd + 3 * 512);                                    \
    gld16(_vs + 0 * 512, _vd + 0 * 512);                                    \
    gld16(_vs + 1 * 512, _vd + 1 * 512);                                    \
    gld16(_vs + 2 * 512, _vd + 2 * 512);                                    \
    gld16(_vs + 3 * 512, _vd + 3 * 512);                                    \
  }

#define LOAD_BIAS(pp, dst)                                                  \
  {                                                                         \
    const float* _br = rpb + (size_t)h * NSEQ * NSEQ +                      \
                       (size_t)(q0 + w * 16 + lg * 4) * NSEQ +              \
                       (pp) * 128 + lr;                                     \
    _Pragma("unroll")                                                       \
    for (int _ct = 0; _ct < 8; ++_ct)                                       \
      _Pragma("unroll")                                                     \
      for (int _r = 0; _r < 4; ++_r)                                        \
        dst[_ct][_r] = _br[(size_t)_r * NSEQ + _ct * 16];                   \
  }

  bf16x8 qf[2];
  {
    const ushort* qrow =
        qb + ((size_t)(bh * NSEQ) + q0 + w * 16 + lr) * HD + lg * 8;
    qf[0] = *(const bf16x8*)qrow;
    qf[1] = *(const bf16x8*)(qrow + 32);
  }
  f32x4 oacc[4];
  float m_run[4], l_run[4];
#pragma unroll
  for (int r = 0; r < 4; ++r) { m_run[r] = -1e30f; l_run[r] = 0.f; }
#pragma unroll
  for (int dt = 0; dt < 4; ++dt) oacc[dt] = (f32x4){0.f, 0.f, 0.f, 0.f};

  float bias_c[8][4], bias_n[8][4];

  ISSUE(p0, 0);
  LOAD_BIAS(p0, bias_c);
  ISSUE(p0 + 1, 1);
  int curb = 0;

  for (int p = p0; p < p1; ++p) {
    if (p < p1 - 1) {
      asm volatile("s_waitcnt vmcnt(40)" ::: "memory");
    } else {
      asm volatile("s_waitcnt vmcnt(32)" ::: "memory");
    }
    __builtin_amdgcn_sched_barrier(0);
    __builtin_amdgcn_s_barrier();

    const char* Kc = (const char*)(Ks + curb * 8192);
    const char* Vc = (const char*)(Vs + curb * 8192);
    f32x4 s[8];
    __builtin_amdgcn_s_setprio(1);
#pragma unroll
    for (int ct = 0; ct < 8; ++ct) {
      s[ct] = (f32x4){0.f, 0.f, 0.f, 0.f};
      const int krow = ct * 16 + lr;
#pragma unroll
      for (int kk = 0; kk < 2; ++kk) {
        bf16x8 kf = *(const bf16x8*)(Kc + krow * 128 +
                                     (((kk * 4 + lg) ^ (krow & 7)) << 4));
        s[ct] = __builtin_amdgcn_mfma_f32_16x16x32_bf16(qf[kk], kf, s[ct], 0, 0, 0);
      }
    }
    __builtin_amdgcn_s_setprio(0);
    if (p + 1 < p1) LOAD_BIAS(p + 1, bias_n);
#pragma unroll
    for (int ct = 0; ct < 8; ++ct)
#pragma unroll
      for (int r = 0; r < 4; ++r) s[ct][r] += bias_c[ct][r];
    if (p == pdiag) {
      const int qrel = q0 + w * 16 + lg * 4;
#pragma unroll
      for (int ct = 0; ct < 8; ++ct) {
        const int kg = p * 128 + ct * 16 + lr;
#pragma unroll
        for (int r = 0; r < 4; ++r)
          if (kg > qrel + r) s[ct][r] = -1e30f;
      }
    }
    float fac[4];
#pragma unroll
    for (int r = 0; r < 4; ++r) {
      float mt = s[0][r];
#pragma unroll
      for (int ct = 1; ct < 8; ++ct) mt = fmaxf(mt, s[ct][r]);
#pragma unroll
      for (int msk = 1; msk < 16; msk <<= 1)
        mt = fmaxf(mt, __shfl_xor(mt, msk, 64));
      const float m_new = fmaxf(m_run[r], mt);
      fac[r] = __expf(m_run[r] - m_new);
      m_run[r] = m_new;
      float ls = 0.f;
#pragma unroll
      for (int ct = 0; ct < 8; ++ct) {
        const float pv = __expf(s[ct][r] - m_new);
        s[ct][r] = pv;
        ls += pv;
      }
#pragma unroll
      for (int msk = 1; msk < 16; msk <<= 1) ls += __shfl_xor(ls, msk, 64);
      l_run[r] = l_run[r] * fac[r] + ls;
    }
#pragma unroll
    for (int dt = 0; dt < 4; ++dt)
#pragma unroll
      for (int r = 0; r < 4; ++r) oacc[dt][r] *= fac[r];
    char* Pw = (char*)Ps + w * 4096;
#pragma unroll
    for (int ct = 0; ct < 8; ++ct) {
      uint u01, u23;
      asm("v_cvt_pk_bf16_f32 %0, %1, %2" : "=v"(u01) : "v"(s[ct][0]), "v"(s[ct][1]));
      asm("v_cvt_pk_bf16_f32 %0, %1, %2" : "=v"(u23) : "v"(s[ct][2]), "v"(s[ct][3]));
      const int cbyte = (ct * 16 + lr) * 2;
      const int chv = cbyte >> 4, off = cbyte & 15;
      const int r0 = lg * 4;
      *(ushort*)(Pw + (r0 + 0) * 256 + (((chv ^ (r0 + 0)) << 4) | off)) = (ushort)u01;
      *(ushort*)(Pw + (r0 + 1) * 256 + (((chv ^ (r0 + 1)) << 4) | off)) = (ushort)(u01 >> 16);
      *(ushort*)(Pw + (r0 + 2) * 256 + (((chv ^ (r0 + 2)) << 4) | off)) = (ushort)u23;
      *(ushort*)(Pw + (r0 + 3) * 256 + (((chv ^ (r0 + 3)) << 4) | off)) = (ushort)(u23 >> 16);
    }
    __builtin_amdgcn_s_setprio(1);
#pragma unroll
    for (int kk = 0; kk < 4; ++kk) {
      bf16x8 pf = *(const bf16x8*)(Pw + lr * 256 + (((kk * 4 + lg) ^ lr) << 4));
#pragma unroll
      for (int dt = 0; dt < 4; ++dt) {
        const int vrow = dt * 16 + lr;
        bf16x8 vf = *(const bf16x8*)(Vc + vrow * 256 +
                                     (((kk * 4 + lg) ^ (vrow & 15)) << 4));
        oacc[dt] =
            __builtin_amdgcn_mfma_f32_16x16x32_bf16(pf, vf, oacc[dt], 0, 0, 0);
      }
    }
    __builtin_amdgcn_s_setprio(0);
    __builtin_amdgcn_sched_barrier(0);
    __builtin_amdgcn_s_barrier();
    if (p + 2 < p1) ISSUE(p + 2, curb);
    if (p + 1 < p1) {
#pragma unroll
      for (int ct = 0; ct < 8; ++ct)
#pragma unroll
        for (int r = 0; r < 4; ++r) bias_c[ct][r] = bias_n[ct][r];
    }
    curb ^= 1;
  }
#undef ISSUE
#undef LOAD_BIAS
  if (!partial) {
    // ---- direct epilogue -> SWIZZLED obsw tile image (tile (m>>7, h))
#pragma unroll
    for (int r = 0; r < 4; ++r) {
      const int qg = q0 + w * 16 + lg * 4 + r;
      const int m = bb * NSEQ + qg;
      const int row = m & 127, mt = m >> 7;
      const int rs = row & 7;
      ushort* tb = obsw + (size_t)(mt * 8 + h) * 8192 + row * 64;
      const float inv = 1.0f / l_run[r];
#pragma unroll
      for (int dt = 0; dt < 4; ++dt) {
        const int d = dt * 16 + lr;
        tb[(((d >> 3) ^ rs) << 3) + (d & 7)] = f2bf(oacc[dt][r] * inv);
      }
    }
  } else {
    float* slot =
        scratch + (size_t)((bh * 16 + (qt - 16)) * 2 + ch) * SLOT_F;
#pragma unroll
    for (int r = 0; r < 4; ++r) {
      const int row = w * 16 + lg * 4 + r;
#pragma unroll
      for (int dt = 0; dt < 4; ++dt)
        slot[row * 64 + dt * 16 + lr] = oacc[dt][r];
      if (lr == 0) {
        slot[4096 + row] = m_run[r];
        slot[4160 + row] = l_run[r];
      }
    }
  }
}

// ---------------- Kernel: 2-way merge for qt >= 16 -> swizzled obsw --------
__global__ __launch_bounds__(256) void attn_merge_kernel(
    const float* __restrict__ scratch, ushort* __restrict__ obsw) {
  const int bid = blockIdx.x;        // 16 bh x 16 qt
  const int bh = bid >> 4;
  const int qt = 16 + (bid & 15);
  const int bb = bh >> 3, h = bh & 7;
  const float* s0 = scratch + (size_t)((bh * 16 + (qt - 16)) * 2) * SLOT_F;
  const float* s1 = s0 + SLOT_F;
  const int t = threadIdx.x;
  const int r = t >> 2;
  const int c0 = (t & 3) * 16;
  const float m0 = s0[4096 + r], m1 = s1[4096 + r];
  const float M = fmaxf(m0, m1);
  const float sc0 = __expf(m0 - M), sc1 = __expf(m1 - M);
  const float L = s0[4160 + r] * sc0 + s1[4160 + r] * sc1;
  const float inv = 1.0f / L;
  ushort tmp[16];
#pragma unroll
  for (int j4 = 0; j4 < 4; ++j4) {
    float4 a = *(const float4*)(s0 + r * 64 + c0 + j4 * 4);
    float4 b = *(const float4*)(s1 + r * 64 + c0 + j4 * 4);
    tmp[j4 * 4 + 0] = f2bf((a.x * sc0 + b.x * sc1) * inv);
    tmp[j4 * 4 + 1] = f2bf((a.y * sc0 + b.y * sc1) * inv);
    tmp[j4 * 4 + 2] = f2bf((a.z * sc0 + b.z * sc1) * inv);
    tmp[j4 * 4 + 3] = f2bf((a.w * sc0 + b.w * sc1) * inv);
  }
  const int m = bb * NSEQ + qt * 64 + r;
  const int row = m & 127, mt = m >> 7;
  const int rs = row & 7;
  ushort* tb = obsw + (size_t)(mt * 8 + h) * 8192 + row * 64;
  *(uint4*)(tb + ((((c0 >> 3) + 0) ^ rs) << 3)) = *(const uint4*)&tmp[0];
  *(uint4*)(tb + ((((c0 >> 3) + 1) ^ rs) << 3)) = *(const uint4*)&tmp[8];
}

extern "C" void kernel_launch(void* const* d_in, const int* in_sizes, int n_in,
                              void* d_out, int out_size, void* d_ws, size_t ws_size,
                              hipStream_t stream) {
  (void)in_sizes; (void)n_in; (void)out_size; (void)ws_size;
  const float* x = (const float*)d_in[0];
  const float* rpb = (const float*)d_in[1];
  const float* Wq = (const float*)d_in[2];
  const float* Wkv = (const float*)d_in[3];
  const float* Wo = (const float*)d_in[4];
  const float* bo = (const float*)d_in[5];
  float* out = (float*)d_out;

  ushort* qbb = (ushort*)d_ws;                           // 16*2048*64
  ushort* ksw = qbb + (size_t)NB * NH * NSEQ * HD;       // 2*32 tiles x 8KB
  ushort* vsw = ksw + (size_t)NB * NSEQ * HD;            // 2*16 pair-tiles
  ushort* obsw = vsw + (size_t)NB * NSEQ * HD;           // 32x8 swz tiles (4MB)
  ushort* xsw = obsw + (size_t)NB * NSEQ * DINNER;       // 32x16 swz tiles (8MB)
  ushort* WT1sw = xsw + (size_t)NB * NSEQ * DMODEL;      // 10x16 swz tiles
  ushort* WoTsw = WT1sw + (size_t)640 * DMODEL;          // 16x8 swz tiles
  float* scratch = (float*)(WoTsw + (size_t)DMODEL * DINNER);  // 512*4224 f32

  prep_kernel<<<dim3(800), 256, 0, stream>>>(x, Wq, Wkv, Wo, xsw, WT1sw, WoTsw);
  qkv_mfma_kernel<<<dim3(32, 5), 256, 0, stream>>>(xsw, WT1sw, qbb, ksw, vsw);
  attn_mfma_kernel<<<dim3(768), 256, 0, stream>>>(qbb, ksw, vsw, rpb, obsw,
                                                  scratch);
  attn_merge_kernel<<<dim3(256), 256, 0, stream>>>(scratch, obsw);
  out_mfma_kernel<<<dim3(32, 8), 256, 0, stream>>>(obsw, WoTsw, bo, out);
}

// Round 17
// 83.025 us; speedup vs baseline: 1.0433x; 1.0433x over previous
//
#include <hip/hip_runtime.h>

#define NSEQ 2048
#define NB 2
#define NH 8
#define HD 64
#define DMODEL 1024
#define DINNER 512   // NH*HD

// partial slot for k-split tiles: O[64][64] f32 + m[64] + l[64]
#define SLOT_F 4224
#define LOG2E 1.44269504f

typedef __attribute__((ext_vector_type(8))) short bf16x8;
typedef __attribute__((ext_vector_type(4))) float f32x4;

__device__ __forceinline__ ushort f2bf(float f) {
  uint u = __float_as_uint(f);
  uint r = (u + 0x7fffu + ((u >> 16) & 1u)) >> 16;
  return (ushort)r;
}

// async global->LDS, 16B per lane; LDS dest is wave-uniform base (+lane*16 by HW)
__device__ __forceinline__ void gld16(const ushort* g, ushort* l) {
  __builtin_amdgcn_global_load_lds(
      (const __attribute__((address_space(1))) uint*)g,
      (__attribute__((address_space(3))) uint*)l, 16, 0, 0);
}

// ---------------- prep: BOTH weight transposes in one launch ----------------
// id < 160: WT1[640][1024] <- [Wq | Wkv]   (16 x 10 tiles)
// id >= 160: WoT[1024][512] <- Wo          (8 x 16 tiles)
__global__ __launch_bounds__(256) void transpose_cast_both_kernel(
    const float* __restrict__ Wq, const float* __restrict__ Wkv,
    const float* __restrict__ Wo, ushort* __restrict__ WT1,
    ushort* __restrict__ WoT) {
  __shared__ float t[64][65];
  const int id = blockIdx.x;
  const float *srcA, *srcB;
  int ldA, ldB, nsplit, Ktot, k0, n0;
  ushort* dst;
  if (id < 160) {
    k0 = (id & 15) * 64; n0 = (id >> 4) * 64;
    srcA = Wq; srcB = Wkv; ldA = 512; ldB = 128; nsplit = 512;
    Ktot = 1024; dst = WT1;
  } else {
    const int u = id - 160;
    k0 = (u & 7) * 64; n0 = (u >> 3) * 64;
    srcA = Wo; srcB = Wo; ldA = 1024; ldB = 1024; nsplit = 1024;
    Ktot = 512; dst = WoT;
  }
  const float* src; int ld, nb;
  if (n0 < nsplit) { src = srcA; ld = ldA; nb = n0; }
  else { src = srcB; ld = ldB; nb = n0 - nsplit; }
  const int r = threadIdx.x >> 4;
  const int c = (threadIdx.x & 15) * 4;
#pragma unroll
  for (int rr = r; rr < 64; rr += 16) {
    float4 v = *(const float4*)(src + (size_t)(k0 + rr) * ld + nb + c);
    t[rr][c + 0] = v.x; t[rr][c + 1] = v.y; t[rr][c + 2] = v.z; t[rr][c + 3] = v.w;
  }
  __syncthreads();
#pragma unroll
  for (int rr = r; rr < 64; rr += 16) {
    ushort4 o;
    o.x = f2bf(t[c + 0][rr]); o.y = f2bf(t[c + 1][rr]);
    o.z = f2bf(t[c + 2][rr]); o.w = f2bf(t[c + 3][rr]);
    *(ushort4*)(dst + (size_t)(n0 + rr) * Ktot + k0 + c) = o;
  }
}

// ---------------- GEMM staging helpers (128x64 tile, BK=64) ----------------
__device__ __forceinline__ void stageA_bf16(const ushort* __restrict__ src, int ld,
                                            int row0, int k0, ushort* lds, int tid) {
#pragma unroll
  for (int i = 0; i < 4; ++i) {
    const int cix = i * 256 + tid;
    const int row = cix >> 3, j = cix & 7;
    uint4 v = *(const uint4*)(src + (size_t)(row0 + row) * ld + k0 + j * 8);
    *(uint4*)((char*)lds + row * 128 + ((j ^ (row & 7)) << 4)) = v;
  }
}
__device__ __forceinline__ void stageA_f32(const float* __restrict__ src, int ld,
                                           int row0, int k0, ushort* lds, int tid) {
#pragma unroll
  for (int i = 0; i < 4; ++i) {
    const int cix = i * 256 + tid;
    const int row = cix >> 3, j = cix & 7;
    const float* p = src + (size_t)(row0 + row) * ld + k0 + j * 8;
    float4 a = *(const float4*)p;
    float4 b = *(const float4*)(p + 4);
    uint u0, u1, u2, u3;
    asm("v_cvt_pk_bf16_f32 %0, %1, %2" : "=v"(u0) : "v"(a.x), "v"(a.y));
    asm("v_cvt_pk_bf16_f32 %0, %1, %2" : "=v"(u1) : "v"(a.z), "v"(a.w));
    asm("v_cvt_pk_bf16_f32 %0, %1, %2" : "=v"(u2) : "v"(b.x), "v"(b.y));
    asm("v_cvt_pk_bf16_f32 %0, %1, %2" : "=v"(u3) : "v"(b.z), "v"(b.w));
    uint4 v; v.x = u0; v.y = u1; v.z = u2; v.w = u3;
    *(uint4*)((char*)lds + row * 128 + ((j ^ (row & 7)) << 4)) = v;
  }
}
__device__ __forceinline__ void stageB(const ushort* __restrict__ src, int ld,
                                       int row0, int k0, ushort* lds, int tid) {
#pragma unroll
  for (int i = 0; i < 2; ++i) {
    const int cix = i * 256 + tid;
    const int row = cix >> 3, j = cix & 7;
    uint4 v = *(const uint4*)(src + (size_t)(row0 + row) * ld + k0 + j * 8);
    *(uint4*)((char*)lds + row * 128 + ((j ^ (row & 7)) << 4)) = v;
  }
}

// ---------------- Kernel: QKV GEMM, fused x-cast (bf16 MFMA) ----------------
// 128x64 tile; grid (32, 10). by<8 -> q (scaled); by==8 -> k; by==9 -> v.
__global__ __launch_bounds__(256) void qkv_mfma_kernel(
    const float* __restrict__ x, const ushort* __restrict__ WT1,
    ushort* __restrict__ qb, ushort* __restrict__ ksw, ushort* __restrict__ vsw) {
  __shared__ ushort As[128 * 64];
  __shared__ ushort Bs[64 * 64];
  const int tid = threadIdx.x;
  const int m0 = blockIdx.x * 128, n0 = blockIdx.y * 64;
  const int lane = tid & 63;
  const int w = tid >> 6;
  const int wr = w >> 1, wc = w & 1;
  const int lr = lane & 15, lg = lane >> 4;
  f32x4 acc[4][2];
#pragma unroll
  for (int a = 0; a < 4; ++a)
#pragma unroll
    for (int b = 0; b < 2; ++b) acc[a][b] = (f32x4){0.f, 0.f, 0.f, 0.f};
  for (int k0 = 0; k0 < DMODEL; k0 += 64) {
    __syncthreads();
    stageA_f32(x, DMODEL, m0, k0, As, tid);
    stageB(WT1, DMODEL, n0, k0, Bs, tid);
    __syncthreads();
#pragma unroll
    for (int kk = 0; kk < 2; ++kk) {
      bf16x8 af[4], bfr[2];
#pragma unroll
      for (int mi = 0; mi < 4; ++mi) {
        const int r = wr * 64 + mi * 16 + lr;
        af[mi] = *(const bf16x8*)((char*)As + r * 128 + (((kk * 4 + lg) ^ (r & 7)) << 4));
      }
#pragma unroll
      for (int ni = 0; ni < 2; ++ni) {
        const int r = wc * 32 + ni * 16 + lr;
        bfr[ni] = *(const bf16x8*)((char*)Bs + r * 128 + (((kk * 4 + lg) ^ (r & 7)) << 4));
      }
#pragma unroll
      for (int mi = 0; mi < 4; ++mi)
#pragma unroll
        for (int ni = 0; ni < 2; ++ni)
          acc[mi][ni] = __builtin_amdgcn_mfma_f32_16x16x32_bf16(af[mi], bfr[ni],
                                                                acc[mi][ni], 0, 0, 0);
    }
  }
#pragma unroll
  for (int mi = 0; mi < 4; ++mi)
#pragma unroll
    for (int ni = 0; ni < 2; ++ni) {
      const int n = n0 + wc * 32 + ni * 16 + lr;
#pragma unroll
      for (int r = 0; r < 4; ++r) {
        const int m = m0 + wr * 64 + mi * 16 + lg * 4 + r;
        const int bb = m >> 11, key = m & (NSEQ - 1);
        const float v = acc[mi][ni][r];
        if (blockIdx.y < 8) {
          const int h = n >> 6, d = n & 63;
          qb[((size_t)((bb * NH + h) * NSEQ) + key) * HD + d] = f2bf(v * 0.125f);
        } else if (blockIdx.y == 8) {
          // K swizzled: tile=key>>6, row=key&63; chunk(d>>3) ^ (row&7)
          const int d = n - DINNER;
          const int t = key >> 6, row = key & 63;
          ksw[(size_t)((bb * 32 + t) * 64 + row) * 64 +
              (((d >> 3) ^ (row & 7)) << 3) + (d & 7)] = f2bf(v);
        } else {
          // V^T swizzled per 128-key pair: row=d; chunk(kk>>3) ^ (d&15)
          const int d = n - DINNER - HD;
          const int pr = key >> 7, kk = key & 127;
          vsw[(size_t)((bb * 16 + pr) * 64 + d) * 128 +
              (((kk >> 3) ^ (d & 15)) << 3) + (kk & 7)] = f2bf(v);
        }
      }
    }
}

// ---------------- Kernel: out GEMM (bf16 MFMA) + bias, fp32 out ------------
// 128x64 tile; grid (32, 16).
__global__ __launch_bounds__(256) void out_mfma_kernel(
    const ushort* __restrict__ ab, const ushort* __restrict__ WoT,
    const float* __restrict__ bo, float* __restrict__ out) {
  __shared__ ushort As[128 * 64];
  __shared__ ushort Bs[64 * 64];
  const int tid = threadIdx.x;
  const int m0 = blockIdx.x * 128, n0 = blockIdx.y * 64;
  const int lane = tid & 63;
  const int w = tid >> 6;
  const int wr = w >> 1, wc = w & 1;
  const int lr = lane & 15, lg = lane >> 4;
  f32x4 acc[4][2];
#pragma unroll
  for (int a = 0; a < 4; ++a)
#pragma unroll
    for (int b = 0; b < 2; ++b) acc[a][b] = (f32x4){0.f, 0.f, 0.f, 0.f};
  for (int k0 = 0; k0 < DINNER; k0 += 64) {
    __syncthreads();
    stageA_bf16(ab, DINNER, m0, k0, As, tid);
    stageB(WoT, DINNER, n0, k0, Bs, tid);
    __syncthreads();
#pragma unroll
    for (int kk = 0; kk < 2; ++kk) {
      bf16x8 af[4], bfr[2];
#pragma unroll
      for (int mi = 0; mi < 4; ++mi) {
        const int r = wr * 64 + mi * 16 + lr;
        af[mi] = *(const bf16x8*)((char*)As + r * 128 + (((kk * 4 + lg) ^ (r & 7)) << 4));
      }
#pragma unroll
      for (int ni = 0; ni < 2; ++ni) {
        const int r = wc * 32 + ni * 16 + lr;
        bfr[ni] = *(const bf16x8*)((char*)Bs + r * 128 + (((kk * 4 + lg) ^ (r & 7)) << 4));
      }
#pragma unroll
      for (int mi = 0; mi < 4; ++mi)
#pragma unroll
        for (int ni = 0; ni < 2; ++ni)
          acc[mi][ni] = __builtin_amdgcn_mfma_f32_16x16x32_bf16(af[mi], bfr[ni],
                                                                acc[mi][ni], 0, 0, 0);
    }
  }
#pragma unroll
  for (int mi = 0; mi < 4; ++mi)
#pragma unroll
    for (int ni = 0; ni < 2; ++ni) {
      const int n = n0 + wc * 32 + ni * 16 + lr;
      const float bias = bo[n];
#pragma unroll
      for (int r = 0; r < 4; ++r) {
        const int m = m0 + wr * 64 + mi * 16 + lg * 4 + r;
        out[(size_t)m * DMODEL + n] = acc[mi][ni][r] + bias;
      }
    }
}

// ---------------- Kernel: causal flash attention (R8-best) -----------------
// Work items (768 blocks, longest-first dispatch):
//  id [0,256):   qt=16+(id>>4), chunk 0 (pairs 0..7)  -> partial
//  id [256,512): qt=31-((id-256)>>4), chunk 1 (pairs 8..np-1) -> partial
//  id [512,768): qt=15-((id-512)>>4), whole (pairs 0..np-1)   -> direct
__global__ __launch_bounds__(256) void attn_mfma_kernel(
    const ushort* __restrict__ qb, const ushort* __restrict__ ksw,
    const ushort* __restrict__ vsw, const float* __restrict__ rpb,
    ushort* __restrict__ ob, float* __restrict__ scratch) {
  __shared__ ushort Ks[2 * 128 * 64];   // dbuf: [key 128][d-chunk swz] 16KB each
  __shared__ ushort Vs[2 * 64 * 128];   // dbuf: [d 64][key-chunk swz] 16KB each
  __shared__ ushort Ps[4 * 16 * 128];   // per-wave P [qrow 16][key 128] swz
  const int tid = threadIdx.x;
  const int lane = tid & 63;
  const int w = tid >> 6;
  const int id = blockIdx.x;
  const int bh = id & 15;
  int qt, ch, p0, p1, partial;
  if (id < 256) {
    qt = 16 + (id >> 4); ch = 0; p0 = 0; p1 = 8; partial = 1;
  } else if (id < 512) {
    qt = 31 - ((id - 256) >> 4); ch = 1; p0 = 8; p1 = (qt >> 1) + 1; partial = 1;
  } else {
    qt = 15 - ((id - 512) >> 4); ch = 0; p0 = 0; p1 = (qt >> 1) + 1; partial = 0;
  }
  const int bb = bh >> 3, h = bh & 7;
  const int q0 = qt * 64;
  const int lr = lane & 15;
  const int lg = lane >> 4;
  const int pdiag = qt >> 1;

  const ushort* kpair = ksw + (size_t)bb * 32 * 64 * 64;
  const ushort* vpair = vsw + (size_t)bb * 16 * 64 * 128;
  const ushort* ksrcw = kpair + w * 2048 + lane * 8;
  const ushort* vsrcw = vpair + w * 2048 + lane * 8;
  ushort* kdstw = Ks + w * 2048;
  ushort* vdstw = Vs + w * 2048;

#define ISSUE(pp, bsel)                                                     \
  {                                                                         \
    const ushort* _ks = ksrcw + (size_t)(pp) * 8192;                        \
    const ushort* _vs = vsrcw + (size_t)(pp) * 8192;                        \
    ushort* _kd = kdstw + (bsel) * 8192;                                    \
    ushort* _vd = vdstw + (bsel) * 8192;                                    \
    gld16(_ks + 0 * 512, _kd + 0 * 512);                                    \
    gld16(_ks + 1 * 512, _kd + 1 * 512);                                    \
    gld16(_ks + 2 * 512, _kd + 2 * 512);                                    \
    gld16(_ks + 3 * 512, _kd + 3 * 512);                                    \
    gld16(_vs + 0 * 512, _vd + 0 * 512);                                    \
    gld16(_vs + 1 * 512, _vd + 1 * 512);                                    \
    gld16(_vs + 2 * 512, _vd + 2 * 512);                                    \
    gld16(_vs + 3 * 512, _vd + 3 * 512);                                    \
  }

#define LOAD_BIAS(pp, dst)                                                  \
  {                                                                         \
    const float* _br = rpb + (size_t)h * NSEQ * NSEQ +                      \
                       (size_t)(q0 + w * 16 + lg * 4) * NSEQ +              \
                       (pp) * 128 + lr;                                     \
    _Pragma("unroll")                                                       \
    for (int _ct = 0; _ct < 8; ++_ct)                                       \
      _Pragma("unroll")                                                     \
      for (int _r = 0; _r < 4; ++_r)                                        \
        dst[_ct][_r] = _br[(size_t)_r * NSEQ + _ct * 16];                   \
  }

  bf16x8 qf[2];
  {
    const ushort* qrow =
        qb + ((size_t)(bh * NSEQ) + q0 + w * 16 + lr) * HD + lg * 8;
    qf[0] = *(const bf16x8*)qrow;
    qf[1] = *(const bf16x8*)(qrow + 32);
  }
  f32x4 oacc[4];
  float m_run[4], l_run[4];
#pragma unroll
  for (int r = 0; r < 4; ++r) { m_run[r] = -1e30f; l_run[r] = 0.f; }
#pragma unroll
  for (int dt = 0; dt < 4; ++dt) oacc[dt] = (f32x4){0.f, 0.f, 0.f, 0.f};

  float bias_c[8][4], bias_n[8][4];

  ISSUE(p0, 0);
  LOAD_BIAS(p0, bias_c);
  ISSUE(p0 + 1, 1);
  int curb = 0;

  for (int p = p0; p < p1; ++p) {
    if (p < p1 - 1) {
      asm volatile("s_waitcnt vmcnt(40)" ::: "memory");
    } else {
      asm volatile("s_waitcnt vmcnt(32)" ::: "memory");
    }
    __builtin_amdgcn_sched_barrier(0);
    __builtin_amdgcn_s_barrier();

    const char* Kc = (const char*)(Ks + curb * 8192);
    const char* Vc = (const char*)(Vs + curb * 8192);
    f32x4 s[8];
    __builtin_amdgcn_s_setprio(1);
#pragma unroll
    for (int ct = 0; ct < 8; ++ct) {
      s[ct] = (f32x4){0.f, 0.f, 0.f, 0.f};
      const int krow = ct * 16 + lr;
#pragma unroll
      for (int kk = 0; kk < 2; ++kk) {
        bf16x8 kf = *(const bf16x8*)(Kc + krow * 128 +
                                     (((kk * 4 + lg) ^ (krow & 7)) << 4));
        s[ct] = __builtin_amdgcn_mfma_f32_16x16x32_bf16(qf[kk], kf, s[ct], 0, 0, 0);
      }
    }
    __builtin_amdgcn_s_setprio(0);
    if (p + 1 < p1) LOAD_BIAS(p + 1, bias_n);
#pragma unroll
    for (int ct = 0; ct < 8; ++ct)
#pragma unroll
      for (int r = 0; r < 4; ++r) s[ct][r] += bias_c[ct][r];
    if (p == pdiag) {
      const int qrel = q0 + w * 16 + lg * 4;
#pragma unroll
      for (int ct = 0; ct < 8; ++ct) {
        const int kg = p * 128 + ct * 16 + lr;
#pragma unroll
        for (int r = 0; r < 4; ++r)
          if (kg > qrel + r) s[ct][r] = -1e30f;
      }
    }
    float fac[4];
#pragma unroll
    for (int r = 0; r < 4; ++r) {
      float mt = s[0][r];
#pragma unroll
      for (int ct = 1; ct < 8; ++ct) mt = fmaxf(mt, s[ct][r]);
#pragma unroll
      for (int msk = 1; msk < 16; msk <<= 1)
        mt = fmaxf(mt, __shfl_xor(mt, msk, 64));
      const float m_new = fmaxf(m_run[r], mt);
      fac[r] = __expf(m_run[r] - m_new);
      m_run[r] = m_new;
      float ls = 0.f;
#pragma unroll
      for (int ct = 0; ct < 8; ++ct) {
        const float pv = __expf(s[ct][r] - m_new);
        s[ct][r] = pv;
        ls += pv;
      }
#pragma unroll
      for (int msk = 1; msk < 16; msk <<= 1) ls += __shfl_xor(ls, msk, 64);
      l_run[r] = l_run[r] * fac[r] + ls;
    }
#pragma unroll
    for (int dt = 0; dt < 4; ++dt)
#pragma unroll
      for (int r = 0; r < 4; ++r) oacc[dt][r] *= fac[r];
    char* Pw = (char*)Ps + w * 4096;
#pragma unroll
    for (int ct = 0; ct < 8; ++ct) {
      uint u01, u23;
      asm("v_cvt_pk_bf16_f32 %0, %1, %2" : "=v"(u01) : "v"(s[ct][0]), "v"(s[ct][1]));
      asm("v_cvt_pk_bf16_f32 %0, %1, %2" : "=v"(u23) : "v"(s[ct][2]), "v"(s[ct][3]));
      const int cbyte = (ct * 16 + lr) * 2;
      const int chv = cbyte >> 4, off = cbyte & 15;
      const int r0 = lg * 4;
      *(ushort*)(Pw + (r0 + 0) * 256 + (((chv ^ (r0 + 0)) << 4) | off)) = (ushort)u01;
      *(ushort*)(Pw + (r0 + 1) * 256 + (((chv ^ (r0 + 1)) << 4) | off)) = (ushort)(u01 >> 16);
      *(ushort*)(Pw + (r0 + 2) * 256 + (((chv ^ (r0 + 2)) << 4) | off)) = (ushort)u23;
      *(ushort*)(Pw + (r0 + 3) * 256 + (((chv ^ (r0 + 3)) << 4) | off)) = (ushort)(u23 >> 16);
    }
    __builtin_amdgcn_s_setprio(1);
#pragma unroll
    for (int kk = 0; kk < 4; ++kk) {
      bf16x8 pf = *(const bf16x8*)(Pw + lr * 256 + (((kk * 4 + lg) ^ lr) << 4));
#pragma unroll
      for (int dt = 0; dt < 4; ++dt) {
        const int vrow = dt * 16 + lr;
        bf16x8 vf = *(const bf16x8*)(Vc + vrow * 256 +
                                     (((kk * 4 + lg) ^ (vrow & 15)) << 4));
        oacc[dt] =
            __builtin_amdgcn_mfma_f32_16x16x32_bf16(pf, vf, oacc[dt], 0, 0, 0);
      }
    }
    __builtin_amdgcn_s_setprio(0);
    __builtin_amdgcn_sched_barrier(0);
    __builtin_amdgcn_s_barrier();
    if (p + 2 < p1) ISSUE(p + 2, curb);
    if (p + 1 < p1) {
#pragma unroll
      for (int ct = 0; ct < 8; ++ct)
#pragma unroll
        for (int r = 0; r < 4; ++r) bias_c[ct][r] = bias_n[ct][r];
    }
    curb ^= 1;
  }
#undef ISSUE
#undef LOAD_BIAS
  if (!partial) {
#pragma unroll
    for (int r = 0; r < 4; ++r) {
      const int qg = q0 + w * 16 + lg * 4 + r;
      const float inv = 1.0f / l_run[r];
      ushort* dst = ob + ((size_t)(bb * NSEQ) + qg) * DINNER + h * HD + lr;
#pragma unroll
      for (int dt = 0; dt < 4; ++dt) dst[dt * 16] = f2bf(oacc[dt][r] * inv);
    }
  } else {
    float* slot =
        scratch + (size_t)((bh * 16 + (qt - 16)) * 2 + ch) * SLOT_F;
#pragma unroll
    for (int r = 0; r < 4; ++r) {
      const int row = w * 16 + lg * 4 + r;
#pragma unroll
      for (int dt = 0; dt < 4; ++dt)
        slot[row * 64 + dt * 16 + lr] = oacc[dt][r];
      if (lr == 0) {
        slot[4096 + row] = m_run[r];
        slot[4160 + row] = l_run[r];
      }
    }
  }
}

// ---------------- Kernel: 2-way merge for qt >= 16 ----------------
__global__ __launch_bounds__(256) void attn_merge_kernel(
    const float* __restrict__ scratch, ushort* __restrict__ ob) {
  const int bid = blockIdx.x;        // 16 bh x 16 qt
  const int bh = bid >> 4;
  const int qt = 16 + (bid & 15);
  const int bb = bh >> 3, h = bh & 7;
  const float* s0 = scratch + (size_t)((bh * 16 + (qt - 16)) * 2) * SLOT_F;
  const float* s1 = s0 + SLOT_F;
  const int t = threadIdx.x;
  const int r = t >> 2;
  const int c0 = (t & 3) * 16;
  const float m0 = s0[4096 + r], m1 = s1[4096 + r];
  const float M = fmaxf(m0, m1);
  const float sc0 = __expf(m0 - M), sc1 = __expf(m1 - M);
  const float L = s0[4160 + r] * sc0 + s1[4160 + r] * sc1;
  const float inv = 1.0f / L;
  ushort* dst = ob + ((size_t)(bb * NSEQ) + qt * 64 + r) * DINNER + h * HD + c0;
#pragma unroll
  for (int j4 = 0; j4 < 4; ++j4) {
    float4 a = *(const float4*)(s0 + r * 64 + c0 + j4 * 4);
    float4 b = *(const float4*)(s1 + r * 64 + c0 + j4 * 4);
    dst[j4 * 4 + 0] = f2bf((a.x * sc0 + b.x * sc1) * inv);
    dst[j4 * 4 + 1] = f2bf((a.y * sc0 + b.y * sc1) * inv);
    dst[j4 * 4 + 2] = f2bf((a.z * sc0 + b.z * sc1) * inv);
    dst[j4 * 4 + 3] = f2bf((a.w * sc0 + b.w * sc1) * inv);
  }
}

extern "C" void kernel_launch(void* const* d_in, const int* in_sizes, int n_in,
                              void* d_out, int out_size, void* d_ws, size_t ws_size,
                              hipStream_t stream) {
  (void)in_sizes; (void)n_in; (void)out_size; (void)ws_size;
  const float* x = (const float*)d_in[0];
  const float* rpb = (const float*)d_in[1];
  const float* Wq = (const float*)d_in[2];
  const float* Wkv = (const float*)d_in[3];
  const float* Wo = (const float*)d_in[4];
  const float* bo = (const float*)d_in[5];
  float* out = (float*)d_out;

  ushort* qbb = (ushort*)d_ws;                           // 16*2048*64
  ushort* ksw = qbb + (size_t)NB * NH * NSEQ * HD;       // 2*32 tiles (swz)
  ushort* vsw = ksw + (size_t)NB * NSEQ * HD;            // 2*16 pair-tiles (swz)
  ushort* obuf = vsw + (size_t)NB * NSEQ * HD;           // 4096*512 bf16
  ushort* WT1 = obuf + (size_t)NB * NSEQ * DINNER;       // 640*1024 bf16
  ushort* WoT = WT1 + (size_t)640 * DMODEL;              // 1024*512 bf16
  float* scratch = (float*)(WoT + (size_t)DMODEL * DINNER);  // 512*4224 f32

  transpose_cast_both_kernel<<<dim3(288), 256, 0, stream>>>(Wq, Wkv, Wo, WT1, WoT);
  qkv_mfma_kernel<<<dim3(32, 10), 256, 0, stream>>>(x, WT1, qbb, ksw, vsw);
  attn_mfma_kernel<<<dim3(768), 256, 0, stream>>>(qbb, ksw, vsw, rpb, obuf,
                                                  scratch);
  attn_merge_kernel<<<dim3(256), 256, 0, stream>>>(scratch, obuf);
  out_mfma_kernel<<<dim3(32, 16), 256, 0, stream>>>(obuf, WoT, bo, out);
}